// Round 4
// baseline (177.772 us; speedup 1.0000x reference)
//
#include <hip/hip_runtime.h>

#define B_  8
#define C_  64
#define T_  12
#define N_  512
#define E_  8192
#define H_  4
#define CO_ 64
#define G_  (B_ * T_)        // 96
#define EP_ (E_ + N_)        // 8704 edges incl self loops
#define MAXDEG 128

typedef __bf16 bf16x8 __attribute__((ext_vector_type(8)));
typedef unsigned short usx8 __attribute__((ext_vector_type(8)));
typedef float  f32x4  __attribute__((ext_vector_type(4)));

static __device__ __forceinline__ unsigned short f2bf(float f) {
    unsigned int u = __float_as_uint(f);
    return (unsigned short)((u + 0x7fffu + ((u >> 16) & 1u)) >> 16);   // RNE
}
static __device__ __forceinline__ float bf2f(unsigned short s) {
    return __uint_as_float(((unsigned int)s) << 16);
}

// ---------------- K1: Wsrc/Wdst reduction + CSR build (single block) ----------
__global__ __launch_bounds__(512) void k_csr(
    const int* __restrict__ ei, const float* __restrict__ W,
    const float* __restrict__ att_src, const float* __restrict__ att_dst,
    float* __restrict__ Wsrc, float* __restrict__ Wdst,
    int* __restrict__ off, int* __restrict__ srclist)
{
    __shared__ int lcnt[512];
    __shared__ int lscan[512];
    int tid = threadIdx.x;

    // phase 0: Wsrc[c,h] = W[c, h*64:]·att_src[h,:]  (tid<256)
    if (tid < 256) {
        int c = tid & 63, hh = tid >> 6;
        float s1 = 0.f, s2 = 0.f;
        for (int co = 0; co < 64; ++co) {
            float w = W[c * 256 + hh * 64 + co];
            s1 += w * att_src[hh * 64 + co];
            s2 += w * att_dst[hh * 64 + co];
        }
        Wsrc[c * 4 + hh] = s1;
        Wdst[c * 4 + hh] = s2;
    }

    lcnt[tid] = 1;                        // self loop
    __syncthreads();
    for (int e = tid; e < E_; e += 512)
        atomicAdd(&lcnt[ei[E_ + e]], 1);
    __syncthreads();
    int v = lcnt[tid];
    lscan[tid] = v;
    __syncthreads();
    for (int d = 1; d < 512; d <<= 1) {
        int val = (tid >= d) ? lscan[tid - d] : 0;
        __syncthreads();
        lscan[tid] += val;
        __syncthreads();
    }
    int excl = lscan[tid] - v;
    off[tid] = excl;
    if (tid == 511) off[512] = lscan[511];
    lcnt[tid] = excl;                     // repurpose as cursor
    __syncthreads();
    for (int e = tid; e < EP_; e += 512) {
        int d, s;
        if (e < E_) { d = ei[E_ + e]; s = ei[e]; }
        else        { d = e - E_;     s = d; }
        int pos = atomicAdd(&lcnt[d], 1);
        srclist[pos] = s;
    }
}

// ---------------- K2: xt transpose + as_/ad_ logit dots (XCD-swizzled) ----------
__global__ __launch_bounds__(256) void k_prep(
    const float* __restrict__ x, const float* __restrict__ Wsrc,
    const float* __restrict__ Wdst,
    float* __restrict__ xt, float* __restrict__ as_, float* __restrict__ ad_)
{
    __shared__ float xs[64][65];
    int bid  = blockIdx.x;                 // 768 = 8 xcd * 12 g * 8 tiles
    int xcd  = bid & 7;
    int r    = bid >> 3;                   // 0..95
    int g    = xcd * 12 + (r >> 3);
    int tile = r & 7;
    int b    = g / T_, t = g - b * T_;
    int n0   = tile * 64;
    int tid  = threadIdx.x;
    int lane = tid & 63, q = tid >> 6;

    #pragma unroll
    for (int i = 0; i < 16; ++i) {
        int c = q + i * 4;
        xs[c][lane] = x[((size_t)(b * C_ + c) * T_ + t) * N_ + n0 + lane];
    }
    __syncthreads();

    float s1 = 0.f, s2 = 0.f;
    for (int c = 0; c < 64; ++c) {
        float v = xs[c][lane];
        s1 += v * Wsrc[c * 4 + q];
        s2 += v * Wdst[c * 4 + q];
    }
    as_[(size_t)(g * N_ + n0 + lane) * H_ + q] = s1;
    ad_[(size_t)(g * N_ + n0 + lane) * H_ + q] = s2;

    #pragma unroll
    for (int i = 0; i < 16; ++i) {
        int nl = q + i * 4;
        xt[((size_t)(g * N_ + n0 + nl)) * 64 + lane] = xs[lane][nl];
    }
}

// ---------------- K3: edge softmax, lanes=(16 graphs x 4 heads) ----------------
// One block per node n; 6 waves cover 96 graphs. Serial over deg (~17);
// per-lane running max/sum -> NO cross-lane reductions.
__global__ __launch_bounds__(384) void k_alpha(
    const float* __restrict__ as_, const float* __restrict__ ad_,
    const int* __restrict__ off, const int* __restrict__ srclist,
    float* __restrict__ alpha, float* __restrict__ sinv)
{
    int n   = blockIdx.x;
    int tid = threadIdx.x;
    int g   = tid >> 2;                    // 0..95
    int hh  = tid & 3;
    int o0  = off[n], deg = off[n + 1] - o0;

    float advv = ad_[(size_t)(g * N_ + n) * H_ + hh];

    float mx = -1e30f;
    for (int e = 0; e < deg; ++e) {
        int s = srclist[o0 + e];
        float v = as_[(size_t)(g * N_ + s) * H_ + hh] + advv;
        v = v > 0.f ? v : 0.2f * v;
        mx = fmaxf(mx, v);
    }
    float sm = 0.f;
    for (int e = 0; e < deg; ++e) {
        int s = srclist[o0 + e];
        float v = as_[(size_t)(g * N_ + s) * H_ + hh] + advv;
        v = v > 0.f ? v : 0.2f * v;
        float w = __expf(v - mx);
        sm += w;
        alpha[((size_t)g * EP_ + o0 + e) * H_ + hh] = w;
    }
    sinv[(size_t)(g * N_ + n) * H_ + hh] = 1.f / sm;
}

// ---------------- K4: aggregate z[g,n,h,:] = sum_e alpha*xt[src]  ----------------
// XCD-swizzled; wave per (g,n), lane = channel.
__global__ __launch_bounds__(256) void k_aggr(
    const float* __restrict__ xt, const float* __restrict__ alpha,
    const float* __restrict__ sinv,
    const int* __restrict__ off, const int* __restrict__ srclist,
    float* __restrict__ z)
{
    __shared__ float wbuf[4][MAXDEG][4];
    __shared__ int   ssrc[4][MAXDEG];
    int wave = threadIdx.x >> 6;
    int lane = threadIdx.x & 63;
    int xcd  = blockIdx.x & 7, slot = blockIdx.x >> 3;
    int g    = xcd * 12 + (slot >> 7);
    int n    = (slot & 127) * 4 + wave;
    int o0   = off[n];
    int deg  = off[n + 1] - o0;

    float4 inv = *reinterpret_cast<const float4*>(&sinv[(size_t)(g * N_ + n) * H_]);
    for (int e = lane; e < deg; e += 64) {
        float4 a = *reinterpret_cast<const float4*>(&alpha[((size_t)g * EP_ + o0 + e) * H_]);
        wbuf[wave][e][0] = a.x * inv.x;
        wbuf[wave][e][1] = a.y * inv.y;
        wbuf[wave][e][2] = a.z * inv.z;
        wbuf[wave][e][3] = a.w * inv.w;
        ssrc[wave][e] = srclist[o0 + e];
    }
    __syncthreads();

    float z0 = 0.f, z1 = 0.f, z2 = 0.f, z3 = 0.f;
    for (int e = 0; e < deg; ++e) {
        int s = ssrc[wave][e];
        float xv = xt[((size_t)(g * N_ + s)) * 64 + lane];
        z0 += wbuf[wave][e][0] * xv;
        z1 += wbuf[wave][e][1] * xv;
        z2 += wbuf[wave][e][2] * xv;
        z3 += wbuf[wave][e][3] * xv;
    }
    size_t base = ((size_t)(g * N_ + n)) * 256;
    z[base +   0 + lane] = z0;
    z[base +  64 + lane] = z1;
    z[base + 128 + lane] = z2;
    z[base + 192 + lane] = z3;
}

// ---------------- K5: out = 0.25*z@Wcat + bias, fused transpose (XCD-swizzled) ---
__global__ __launch_bounds__(256) void k_out(
    const float* __restrict__ z, const float* __restrict__ W,
    const float* __restrict__ bias, float* __restrict__ out)
{
    __shared__ char lds[65536];
    unsigned short (*Bhi)[4][64][8] = (unsigned short (*)[4][64][8])lds;            // 32KB
    unsigned short (*Blo)[4][64][8] = (unsigned short (*)[4][64][8])(lds + 32768);  // 32KB
    float (*tl)[65] = (float (*)[65])lds;   // aliases Bhi AFTER k-loop barrier

    int bid  = blockIdx.x;                 // 768
    int xcd  = bid & 7;
    int r    = bid >> 3;
    int g    = xcd * 12 + (r >> 3);
    int tile = r & 7;
    int b    = g / T_, t = g - b * T_;
    int n0   = tile * 64;
    int tid  = threadIdx.x;

    #pragma unroll
    for (int it = 0; it < 16; ++it) {
        int flat = (tid + it * 256) * 4;
        int c  = flat >> 8, rr = flat & 255;
        int hh = rr >> 6,  co = rr & 63;
        float4 w = *reinterpret_cast<const float4*>(W + flat);
        int ks = hh * 2 + (c >> 5), kq = (c >> 3) & 3, j = c & 7;
        int nt = co >> 4, l0 = kq * 16 + (co & 15);
        float wv[4] = {w.x, w.y, w.z, w.w};
        #pragma unroll
        for (int u = 0; u < 4; ++u) {
            unsigned short hi = f2bf(wv[u]);
            Bhi[ks][nt][l0 + u][j] = hi;
            Blo[ks][nt][l0 + u][j] = f2bf(wv[u] - bf2f(hi));
        }
    }
    __syncthreads();

    int i = tid >> 6, l = tid & 63;
    int m = l & 15, quad = l >> 4;
    const float* zrow = z + ((size_t)(g * N_) + n0 + i * 16 + m) * 256 + quad * 8;

    f32x4 acc[4];
    #pragma unroll
    for (int nt = 0; nt < 4; ++nt) acc[nt] = (f32x4){0.f, 0.f, 0.f, 0.f};

    #pragma unroll
    for (int ks = 0; ks < 8; ++ks) {
        float av[8];
        *reinterpret_cast<float4*>(&av[0]) = *reinterpret_cast<const float4*>(zrow + ks * 32);
        *reinterpret_cast<float4*>(&av[4]) = *reinterpret_cast<const float4*>(zrow + ks * 32 + 4);
        usx8 uhi, ulo;
        #pragma unroll
        for (int j = 0; j < 8; ++j) {
            unsigned short hi = f2bf(av[j]);
            uhi[j] = hi;
            ulo[j] = f2bf(av[j] - bf2f(hi));
        }
        bf16x8 ahi = __builtin_bit_cast(bf16x8, uhi);
        bf16x8 alo = __builtin_bit_cast(bf16x8, ulo);
        #pragma unroll
        for (int nt = 0; nt < 4; ++nt) {
            bf16x8 bh = *reinterpret_cast<bf16x8*>(&Bhi[ks][nt][l][0]);
            bf16x8 bl = *reinterpret_cast<bf16x8*>(&Blo[ks][nt][l][0]);
            acc[nt] = __builtin_amdgcn_mfma_f32_16x16x32_bf16(ahi, bh, acc[nt], 0, 0, 0);
            acc[nt] = __builtin_amdgcn_mfma_f32_16x16x32_bf16(ahi, bl, acc[nt], 0, 0, 0);
            acc[nt] = __builtin_amdgcn_mfma_f32_16x16x32_bf16(alo, bh, acc[nt], 0, 0, 0);
        }
    }
    __syncthreads();

    #pragma unroll
    for (int nt = 0; nt < 4; ++nt) {
        int co = nt * 16 + m;
        float bv = bias[co];
        #pragma unroll
        for (int rr = 0; rr < 4; ++rr) {
            int row = i * 16 + quad * 4 + rr;
            tl[row][co] = 0.25f * acc[nt][rr] + bv;
        }
    }
    __syncthreads();

    #pragma unroll
    for (int it = 0; it < 16; ++it) {
        int c = i + it * 4;
        out[((size_t)(b * CO_ + c) * T_ + t) * N_ + n0 + l] = tl[l][c];
    }
}

extern "C" void kernel_launch(void* const* d_in, const int* in_sizes, int n_in,
                              void* d_out, int out_size, void* d_ws, size_t ws_size,
                              hipStream_t stream) {
    const float* x       = (const float*)d_in[0];
    const int*   ei      = (const int*)  d_in[1];
    const float* W       = (const float*)d_in[2];
    const float* att_src = (const float*)d_in[3];
    const float* att_dst = (const float*)d_in[4];
    const float* bias    = (const float*)d_in[5];
    float* out = (float*)d_out;

    char* p = (char*)d_ws;
    float* z       = (float*)p;  p += (size_t)G_ * N_ * H_ * CO_ * sizeof(float); // 50.3 MB
    float* alpha   = (float*)p;  p += (size_t)G_ * EP_ * H_ * sizeof(float);      // 13.4 MB
    float* xt      = (float*)p;  p += (size_t)G_ * N_ * C_ * sizeof(float);       // 12.6 MB
    float* as_     = (float*)p;  p += (size_t)G_ * N_ * H_ * sizeof(float);
    float* ad_     = (float*)p;  p += (size_t)G_ * N_ * H_ * sizeof(float);
    float* sinv    = (float*)p;  p += (size_t)G_ * N_ * H_ * sizeof(float);
    float* Wsrc    = (float*)p;  p += C_ * H_ * sizeof(float);
    float* Wdst    = (float*)p;  p += C_ * H_ * sizeof(float);
    int* off       = (int*)p;    p += 516 * sizeof(int);
    int* srclist   = (int*)p;    p += EP_ * sizeof(int);

    k_csr   <<<1,           512, 0, stream>>>(ei, W, att_src, att_dst, Wsrc, Wdst, off, srclist);
    k_prep  <<<G_ * 8,      256, 0, stream>>>(x, Wsrc, Wdst, xt, as_, ad_);
    k_alpha <<<N_,          384, 0, stream>>>(as_, ad_, off, srclist, alpha, sinv);
    k_aggr  <<<G_ * N_ / 4, 256, 0, stream>>>(xt, alpha, sinv, off, srclist, z);
    k_out   <<<G_ * 8,      256, 0, stream>>>(z, W, bias, out);
}